// Round 12
// baseline (953.768 us; speedup 1.0000x reference)
//
#include <hip/hip_runtime.h>
#include <hip/hip_cooperative_groups.h>

#define HDIM 128
#define ECHUNK 2048       // edges per scatter chunk
#define CAPLOG 6          // 64 slots per node (max in-degree ~35 << 64)

// Harness contract (pinned empirically, rounds 1-3):
//   float32 tensors -> const float* ; int64 edge_index -> const int* ; output -> float*
//
// R23 = R22 with the compile error fixed (cursorload helper was declared
// AFTER its use; replaced with a direct P.cursor[node] load). R22 theory
// unchanged: R21's mono-coop absmax 0.457 == all-zero-output signature
// (unchecked coop-launch error) OR grid.sync cross-XCD fence gap (G16).
// Mitigations: (a) launch ladder 1024 -> 512 -> PROVEN R20 5-kernel
// fallback (enqueue return code checked host-side, no sync); (b) explicit
// device-scope __threadfence() before every grid.sync(). Mono algebra is
// isomorphic to R20 (audited): cursor = pure counts, self-loop added
// algebraically in agg epilogue, dinv computed once.

namespace cg = cooperative_groups;

typedef float f32x4v __attribute__((ext_vector_type(4)));

__device__ __forceinline__ float4 ntload4(const float* p) {
    f32x4v v = __builtin_nontemporal_load((const f32x4v*)p);
    return make_float4(v.x, v.y, v.z, v.w);
}

struct GParams {
    const int* ei; const float* X;
    const float* W1; const float* b1; const float* W2; const float* b2;
    const float* Wfc; const float* bfc;
    float* out;
    float* Qsc; float* Psc; float* dinv; float* Wall; float* bWc;
    int* cursor; unsigned* srcW;
    int N, E, NCH, PART;
};

// ================= mono (cooperative) path =================

// agg pass: 2 nodes/wave parallel (R20-proven core). cursor = counts.
// Self-loop added in epilogue (acc += rows[node]).
// MODE 0: Psc[i] = di*(di*acc + bW)   MODE 1: out[i] = di*acc + cvec
template <int MODE>
__device__ __forceinline__ void agg_pass(const float* __restrict__ rows,
                                         float* __restrict__ outp,
                                         const float* __restrict__ bvec,
                                         const int* __restrict__ cursor,
                                         const unsigned* __restrict__ srcW,
                                         const float* __restrict__ dinv,
                                         int n, int bid, int tid, int nblocks) {
    int w = tid >> 6, lane = tid & 63;
    int grp = lane >> 5, il = lane & 31, sl = il >> 1, half = il & 1;
    float4 bb = ((const float4*)bvec)[half];
    for (int base = bid * 8; base < n; base += nblocks * 8) {
        int node = base + w * 2 + grp;
        if (node < n) {
            int cnt = cursor[node];
            if (cnt > (1 << CAPLOG)) cnt = (1 << CAPLOG);   // paranoia (never taken)
            int s = node << CAPLOG, e = s + cnt;
            float4 acc = make_float4(0.f, 0.f, 0.f, 0.f);
            for (int j = s + sl; j < e; j += 32) {
                unsigned id0 = srcW[j];
                int j2 = j + 16;
                unsigned id1 = (j2 < e) ? srcW[j2] : 0u;
                float4 v0 = *(const float4*)(rows + (size_t)id0 * 8 + half * 4);
                acc.x += v0.x; acc.y += v0.y; acc.z += v0.z; acc.w += v0.w;
                if (j2 < e) {
                    float4 v1 = *(const float4*)(rows + (size_t)id1 * 8 + half * 4);
                    acc.x += v1.x; acc.y += v1.y; acc.z += v1.z; acc.w += v1.w;
                }
            }
#pragma unroll
            for (int off = 2; off < 32; off <<= 1) {   // 2,4,8,16: complete reduce over sl
                acc.x += __shfl_xor(acc.x, off, 64);
                acc.y += __shfl_xor(acc.y, off, 64);
                acc.z += __shfl_xor(acc.z, off, 64);
                acc.w += __shfl_xor(acc.w, off, 64);
            }
            if (il < 2) {
                float4 sv = *(const float4*)(rows + (size_t)node * 8 + half * 4);
                acc.x += sv.x; acc.y += sv.y; acc.z += sv.z; acc.w += sv.w;
                float di = dinv[node];
                float4 o;
                if (MODE == 0) {
                    float a = di * di;
                    o = make_float4(fmaf(a, acc.x, di * bb.x), fmaf(a, acc.y, di * bb.y),
                                    fmaf(a, acc.z, di * bb.z), fmaf(a, acc.w, di * bb.w));
                } else {
                    o = make_float4(fmaf(di, acc.x, bb.x), fmaf(di, acc.y, bb.y),
                                    fmaf(di, acc.z, bb.z), fmaf(di, acc.w, bb.w));
                }
                *(float4*)(outp + (size_t)node * 8 + half * 4) = o;
            }
        }
    }
}

__global__ __launch_bounds__(256, 4) void k_mono(GParams P) {
    cg::grid_group grid = cg::this_grid();
    __shared__ float shbuf[1056];          // phase0: w2f[1024]; phase2: padded Wall
    const int tid = threadIdx.x, bid = blockIdx.x;
    const int NB = gridDim.x;              // multiple of 8

    // ---- phase 0: cursor zero (counts) + weight collapse ----
    for (int i = bid * 256 + tid; i < P.N; i += NB * 256) P.cursor[i] = 0;
    if (bid < 16) {
        for (int i = tid; i < 1024; i += 256) {
            int k = i >> 3, c = i & 7;
            float s = 0.f;
            for (int m = 0; m < 128; m++)
                s = fmaf(P.W2[k * 128 + m], P.Wfc[m * 8 + c], s);
            shbuf[i] = s;
        }
        __syncthreads();
        if (tid < 64) {
            int f = bid * 8 + (tid >> 3), c = tid & 7;
            float s = 0.f;
            for (int k = 0; k < 128; k++)
                s = fmaf(P.W1[f * 128 + k], shbuf[k * 8 + c], s);
            P.Wall[f * 8 + c] = s;
        }
        if (bid == 0) {
            if (tid >= 64 && tid < 72) {           // bW[c] = sum_k b1[k] w2f[k][c]
                int c = tid - 64;
                float s = 0.f;
                for (int k = 0; k < 128; k++) s = fmaf(P.b1[k], shbuf[k * 8 + c], s);
                P.bWc[c] = s;
            } else if (tid >= 72 && tid < 80) {    // cvec[c] = sum_m b2[m] Wfc[m][c]+bfc[c]
                int c = tid - 72;
                float s = P.bfc[c];
                for (int m = 0; m < 128; m++) s = fmaf(P.b2[m], P.Wfc[m * 8 + c], s);
                P.bWc[8 + c] = s;
            }
        }
    }
    __threadfence();                       // device-scope: publish Wall/bWc/cursor zeros
    grid.sync();

    // ---- phase 1: partitioned scatter (p = bid&7 -> XCD-pure; exact chunk split) ----
    {
        const int* cols = P.ei + P.E;
        const int p = bid & 7;
        const int plo = p * P.PART;
        const int chstride = NB >> 3;
        for (int ch = bid >> 3; ch < P.NCH; ch += chstride) {
            int ebase = ch * ECHUNK + tid * 8;
            int eend = ch * ECHUNK + ECHUNK; if (eend > P.E) eend = P.E;
#pragma unroll
            for (int gi = 0; gi < 2; gi++) {
                int e4 = ebase + gi * 4;
                if (e4 + 4 <= eend) {
                    int4 cc = *(const int4*)(cols + e4);
                    int4 rr = *(const int4*)(P.ei + e4);
                    int cv[4] = {cc.x, cc.y, cc.z, cc.w};
                    int rv[4] = {rr.x, rr.y, rr.z, rr.w};
#pragma unroll
                    for (int u = 0; u < 4; u++) {
                        if ((unsigned)(cv[u] - plo) < (unsigned)P.PART) {
                            int c2 = atomicAdd(&P.cursor[cv[u]], 1);
                            if (c2 < (1 << CAPLOG))
                                P.srcW[((size_t)(unsigned)cv[u] << CAPLOG) + c2] = (unsigned)rv[u];
                        }
                    }
                } else {
                    for (int e = e4; e < eend; e++) {
                        int c = cols[e];
                        if ((unsigned)(c - plo) < (unsigned)P.PART) {
                            int c2 = atomicAdd(&P.cursor[c], 1);
                            if (c2 < (1 << CAPLOG))
                                P.srcW[((size_t)(unsigned)c << CAPLOG) + c2] = (unsigned)P.ei[e];
                        }
                    }
                }
            }
        }
    }
    __threadfence();                       // publish srcW stores + cursor counts
    grid.sync();

    // ---- phase 2: qproj Qsc[i] = dinv[i]*(X[i]·Wall), dinv stored ----
    {
        {
            int i4 = tid * 4;
            float4 wv = ((const float4*)P.Wall)[tid];
            int o = i4 + ((i4 >> 7) << 2);             // +16B pad per 128 floats
            shbuf[o] = wv.x; shbuf[o + 1] = wv.y; shbuf[o + 2] = wv.z; shbuf[o + 3] = wv.w;
        }
        __syncthreads();
        int sub = tid & 7;
        int Gq = (P.N + 31) >> 5;
        for (int nb = bid; nb < Gq; nb += NB) {
            int node = nb * 32 + (tid >> 3);
            if (node < P.N) {
                float acc[8];
#pragma unroll
                for (int c = 0; c < 8; c++) acc[c] = 0.f;
                const float* xr = P.X + (size_t)node * HDIM + sub * 16;
                const float* wbase = shbuf + (sub * 16) * 8 + sub * 4;
#pragma unroll
                for (int j4 = 0; j4 < 4; j4++) {
                    float4 xv = ntload4(xr + j4 * 4);
                    const float* wr = wbase + j4 * 32;
#pragma unroll
                    for (int c = 0; c < 8; c++) acc[c] = fmaf(xv.x, wr[c], acc[c]);
                    wr += 8;
#pragma unroll
                    for (int c = 0; c < 8; c++) acc[c] = fmaf(xv.y, wr[c], acc[c]);
                    wr += 8;
#pragma unroll
                    for (int c = 0; c < 8; c++) acc[c] = fmaf(xv.z, wr[c], acc[c]);
                    wr += 8;
#pragma unroll
                    for (int c = 0; c < 8; c++) acc[c] = fmaf(xv.w, wr[c], acc[c]);
                }
#pragma unroll
                for (int off = 1; off < 8; off <<= 1)
#pragma unroll
                    for (int c = 0; c < 8; c++) acc[c] += __shfl_xor(acc[c], off, 64);
                if (sub < 2) {
                    float di = rsqrtf((float)(P.cursor[node] + 1));   // deg+1
                    if (sub == 0) P.dinv[node] = di;
                    float4 o = make_float4(di * acc[sub * 4 + 0], di * acc[sub * 4 + 1],
                                           di * acc[sub * 4 + 2], di * acc[sub * 4 + 3]);
                    *(float4*)(P.Qsc + (size_t)node * 8 + sub * 4) = o;
                }
            }
        }
    }
    __threadfence();                       // publish Qsc + dinv
    grid.sync();

    // ---- phase 3: agg Q -> Psc ----
    agg_pass<0>(P.Qsc, P.Psc, P.bWc, P.cursor, P.srcW, P.dinv, P.N, bid, tid, NB);
    __threadfence();                       // publish Psc
    grid.sync();

    // ---- phase 4: agg Psc -> out ----
    agg_pass<1>(P.Psc, P.out, P.bWc + 8, P.cursor, P.srcW, P.dinv, P.N, bid, tid, NB);
}

// ================= R20 fallback path (proven, 171.8us) =================

__global__ __launch_bounds__(256) void k_init_w2f(const float* __restrict__ W1,
                                                  const float* __restrict__ b1,
                                                  const float* __restrict__ W2,
                                                  const float* __restrict__ b2,
                                                  const float* __restrict__ Wfc,
                                                  const float* __restrict__ bfc,
                                                  float* __restrict__ Wall,
                                                  float* __restrict__ bWc,
                                                  int* __restrict__ cursor,
                                                  unsigned* __restrict__ srcW,
                                                  int n) {
    int t = threadIdx.x;
    if ((int)blockIdx.x >= 16) {
        int i = ((int)blockIdx.x - 16) * 256 + t;
        if (i < n) {
            cursor[i] = (i << CAPLOG) + 1;
            srcW[(size_t)i << CAPLOG] = (unsigned)i;
        }
        return;
    }
    __shared__ float w2f[128 * 8];
    int j = blockIdx.x;
    for (int i = t; i < 1024; i += 256) {
        int k = i >> 3, c = i & 7;
        float s = 0.f;
        for (int m = 0; m < 128; m++)
            s = fmaf(W2[k * 128 + m], Wfc[m * 8 + c], s);
        w2f[i] = s;
    }
    __syncthreads();
    if (t < 64) {
        int f = j * 8 + (t >> 3), c = t & 7;
        float s = 0.f;
        for (int k = 0; k < 128; k++)
            s = fmaf(W1[f * 128 + k], w2f[k * 8 + c], s);
        Wall[f * 8 + c] = s;
    }
    if (j == 0) {
        if (t >= 64 && t < 72) {
            int c = t - 64;
            float s = 0.f;
            for (int k = 0; k < 128; k++) s = fmaf(b1[k], w2f[k * 8 + c], s);
            bWc[c] = s;
        } else if (t >= 72 && t < 80) {
            int c = t - 72;
            float s = bfc[c];
            for (int m = 0; m < 128; m++) s = fmaf(b2[m], Wfc[m * 8 + c], s);
            bWc[8 + c] = s;
        }
    }
}

__global__ __launch_bounds__(256) void k_scatter(const int* __restrict__ ei,
                                                 int* __restrict__ cursor,
                                                 unsigned* __restrict__ srcW, int E,
                                                 int NCH, int PART) {
    int tid = threadIdx.x;
    int p = blockIdx.x & 7, ch = blockIdx.x >> 3;
    if (ch >= NCH) return;
    const int* cols = ei + E;
    int plo = p * PART;
    int ebase = ch * ECHUNK + tid * 8;
    int eend = ch * ECHUNK + ECHUNK; if (eend > E) eend = E;
#pragma unroll
    for (int gi = 0; gi < 2; gi++) {
        int e4 = ebase + gi * 4;
        if (e4 + 4 <= eend) {
            int4 cc = *(const int4*)(cols + e4);
            int cv[4] = {cc.x, cc.y, cc.z, cc.w};
#pragma unroll
            for (int u = 0; u < 4; u++) {
                if ((unsigned)(cv[u] - plo) < (unsigned)PART) {
                    int r = ei[e4 + u];
                    int pos = atomicAdd(&cursor[cv[u]], 1);
                    if (pos < ((cv[u] + 1) << CAPLOG)) srcW[pos] = (unsigned)r;
                }
            }
        } else {
            for (int e = e4; e < eend; e++) {
                int c = cols[e];
                if ((unsigned)(c - plo) < (unsigned)PART) {
                    int r = ei[e];
                    int pos = atomicAdd(&cursor[c], 1);
                    if (pos < ((c + 1) << CAPLOG)) srcW[pos] = (unsigned)r;
                }
            }
        }
    }
}

__global__ __launch_bounds__(256) void k_qproj(const int* __restrict__ cursor,
                                               const float* __restrict__ X,
                                               const float* __restrict__ Wall,
                                               float* __restrict__ Qsc,
                                               int nrows) {
    __shared__ float wsh[1024 + 32];
    int tid = threadIdx.x;
    {
        int i4 = tid * 4;
        float4 wv = ((const float4*)Wall)[tid];
        int o = i4 + ((i4 >> 7) << 2);
        wsh[o] = wv.x; wsh[o + 1] = wv.y; wsh[o + 2] = wv.z; wsh[o + 3] = wv.w;
    }
    __syncthreads();
    int sub = tid & 7;
    int node = blockIdx.x * 32 + (tid >> 3);
    if (node >= nrows) return;
    float acc[8];
#pragma unroll
    for (int c = 0; c < 8; c++) acc[c] = 0.f;
    const float* xr = X + (size_t)node * HDIM + sub * 16;
    const float* wbase = wsh + (sub * 16) * 8 + sub * 4;
#pragma unroll
    for (int j4 = 0; j4 < 4; j4++) {
        float4 xv = ntload4(xr + j4 * 4);
        const float* wr = wbase + j4 * 32;
#pragma unroll
        for (int c = 0; c < 8; c++) acc[c] = fmaf(xv.x, wr[c], acc[c]);
        wr += 8;
#pragma unroll
        for (int c = 0; c < 8; c++) acc[c] = fmaf(xv.y, wr[c], acc[c]);
        wr += 8;
#pragma unroll
        for (int c = 0; c < 8; c++) acc[c] = fmaf(xv.z, wr[c], acc[c]);
        wr += 8;
#pragma unroll
        for (int c = 0; c < 8; c++) acc[c] = fmaf(xv.w, wr[c], acc[c]);
    }
#pragma unroll
    for (int off = 1; off < 8; off <<= 1)
#pragma unroll
        for (int c = 0; c < 8; c++) acc[c] += __shfl_xor(acc[c], off, 64);
    if (sub < 2) {
        int s = node << CAPLOG;
        float di = rsqrtf((float)(cursor[node] - s));
        float4 o = make_float4(di * acc[sub * 4 + 0], di * acc[sub * 4 + 1],
                               di * acc[sub * 4 + 2], di * acc[sub * 4 + 3]);
        *(float4*)(Qsc + (size_t)node * 8 + sub * 4) = o;
    }
}

template <int MODE>
__global__ __launch_bounds__(256) void k_agg8(const float* __restrict__ rows,
                                              const int* __restrict__ cursor,
                                              const unsigned* __restrict__ srcW,
                                              const float* __restrict__ bvec,
                                              float* __restrict__ outp,
                                              int n) {
    int tid = threadIdx.x, w = tid >> 6, lane = tid & 63;
    int grp = lane >> 5;
    int il = lane & 31, sl = il >> 1, half = il & 1;
    float4 bb = ((const float4*)bvec)[half];
    int node = blockIdx.x * 8 + w * 2 + grp;
    if (node >= n) return;
    int s = node << CAPLOG;
    int e = cursor[node];
    int ecap = s + (1 << CAPLOG);
    if (e > ecap) e = ecap;
    float4 acc = make_float4(0.f, 0.f, 0.f, 0.f);
    for (int j = s + sl; j < e; j += 32) {
        unsigned id0 = srcW[j];
        int j2 = j + 16;
        unsigned id1 = (j2 < e) ? srcW[j2] : 0u;
        float4 v0 = *(const float4*)(rows + (size_t)id0 * 8 + half * 4);
        acc.x += v0.x; acc.y += v0.y; acc.z += v0.z; acc.w += v0.w;
        if (j2 < e) {
            float4 v1 = *(const float4*)(rows + (size_t)id1 * 8 + half * 4);
            acc.x += v1.x; acc.y += v1.y; acc.z += v1.z; acc.w += v1.w;
        }
    }
#pragma unroll
    for (int off = 2; off < 32; off <<= 1) {
        acc.x += __shfl_xor(acc.x, off, 64);
        acc.y += __shfl_xor(acc.y, off, 64);
        acc.z += __shfl_xor(acc.z, off, 64);
        acc.w += __shfl_xor(acc.w, off, 64);
    }
    if (il < 2) {
        float di = rsqrtf((float)(e - s));
        float4 o;
        if (MODE == 0) {
            float a = di * di;
            o = make_float4(fmaf(a, acc.x, di * bb.x), fmaf(a, acc.y, di * bb.y),
                            fmaf(a, acc.z, di * bb.z), fmaf(a, acc.w, di * bb.w));
        } else {
            o = make_float4(fmaf(di, acc.x, bb.x), fmaf(di, acc.y, bb.y),
                            fmaf(di, acc.z, bb.z), fmaf(di, acc.w, bb.w));
        }
        *(float4*)(outp + (size_t)node * 8 + half * 4) = o;
    }
}

extern "C" void kernel_launch(void* const* d_in, const int* in_sizes, int n_in,
                              void* d_out, int out_size, void* d_ws, size_t ws_size,
                              hipStream_t stream) {
    const int N = in_sizes[0] / HDIM;   // 50000
    const int E = in_sizes[1] / 2;      // 800000

    // workspace (~20 MB), no memsets needed
    float* Qsc    = (float*)d_ws;                        // N*8 f32
    float* Psc    = Qsc + (size_t)N * 8;                 // N*8 f32
    float* dinv   = Psc + (size_t)N * 8;                 // N (mono path only)
    float* Wall   = dinv + N;                            // 1024
    float* bWc    = Wall + 1024;                         // 16 (bW | cvec)
    int*   cursor = (int*)(bWc + 16);                    // N
    unsigned* srcW = (unsigned*)(((uintptr_t)(cursor + N) + 255) & ~(uintptr_t)255);  // N*64

    GParams hp;
    hp.ei = (const int*)d_in[1];
    hp.X  = (const float*)d_in[0];
    hp.W1 = (const float*)d_in[2];  hp.b1 = (const float*)d_in[3];
    hp.W2 = (const float*)d_in[4];  hp.b2 = (const float*)d_in[5];
    hp.Wfc = (const float*)d_in[6]; hp.bfc = (const float*)d_in[7];
    hp.out = (float*)d_out;
    hp.Qsc = Qsc; hp.Psc = Psc; hp.dinv = dinv; hp.Wall = Wall; hp.bWc = bWc;
    hp.cursor = cursor; hp.srcW = srcW;
    hp.N = N; hp.E = E;
    hp.NCH = (E + ECHUNK - 1) / ECHUNK;   // 391
    hp.PART = (N + 7) / 8;                // 6250

    void* kargs[] = {(void*)&hp};
    hipError_t err = hipLaunchCooperativeKernel((void*)k_mono, dim3(1024), dim3(256),
                                                kargs, 0, stream);
    if (err != hipSuccess)
        err = hipLaunchCooperativeKernel((void*)k_mono, dim3(512), dim3(256),
                                         kargs, 0, stream);
    if (err != hipSuccess) {
        // ---- proven R20 5-kernel fallback ----
        const int NCH  = hp.NCH;
        const int PART = hp.PART;
        const int Gi   = 16 + (N + 255) / 256;
        const int Gq   = (N + 31) / 32;
        const int Ga   = (N + 7) / 8;
        k_init_w2f<<<Gi, 256, 0, stream>>>(hp.W1, hp.b1, hp.W2, hp.b2, hp.Wfc, hp.bfc,
                                           Wall, bWc, cursor, srcW, N);
        k_scatter<<<8 * NCH, 256, 0, stream>>>(hp.ei, cursor, srcW, E, NCH, PART);
        k_qproj<<<Gq, 256, 0, stream>>>(cursor, hp.X, Wall, Qsc, N);
        k_agg8<0><<<Ga, 256, 0, stream>>>(Qsc, cursor, srcW, bWc, Psc, N);
        k_agg8<1><<<Ga, 256, 0, stream>>>(Psc, cursor, srcW, bWc + 8, hp.out, N);
    }
}

// Round 13
// 171.197 us; speedup vs baseline: 5.5712x; 5.5712x over previous
//
#include <hip/hip_runtime.h>
#include <hip/hip_bf16.h>

#define HDIM 128
#define CDIM 8
#define ECHUNK 2048       // edges per scatter chunk
#define CAPLOG 6          // 64 slots per node (max in-degree+1; balls-in-bins max ~36)

// Harness contract (pinned empirically, rounds 1-3):
//   float32 tensors -> const float* ; int64 edge_index -> const int* ; output -> float*
//
// R24 = exact revert to the R20-proven 5-kernel path (171.8us). R23's
// cooperative mono kernel was CORRECT but 876us: VALUBusy 1.2% / HBM 1.5%
// -- grid.sync() costs ~200us each on a 1024-block grid (4 syncs = the
// kernel). Coop path retired permanently; kernel-boundary sync (~5-10us/
// launch) wins by 40x. Pipeline: init(w2f + 64-slot buckets) -> partitioned
// scatter (R17: XCD-pure, p=bid&7) -> qproj (nt-loads, padded wsh) ->
// agg8<0> -> agg8<1> (R20: 2 nodes/wave parallel TLP, 2-ahead unroll).
// Remaining budget: ~44us structural harness ws-poison fill + ~128us of
// latency-bound gather kernels (4 structural variants converged here).

typedef float f32x4v __attribute__((ext_vector_type(4)));

__device__ __forceinline__ float4 ntload4(const float* p) {
    f32x4v v = __builtin_nontemporal_load((const f32x4v*)p);
    return make_float4(v.x, v.y, v.z, v.w);
}

// ---------- fused init: weight-collapse | cursor/self-slot init ----------
// blocks 0..15: block j computes Wall rows 8j..8j+8 of Wall = W1·(W2·Wfc);
// block 0 also bW = b1'W2Wfc and cvec = b2'Wfc + bfc.
// blocks 16.. : cursor[i] = 64i+1, srcW[64i] = i (self slot).
__global__ __launch_bounds__(256) void k_init_w2f(const float* __restrict__ W1,
                                                  const float* __restrict__ b1,
                                                  const float* __restrict__ W2,
                                                  const float* __restrict__ b2,
                                                  const float* __restrict__ Wfc,
                                                  const float* __restrict__ bfc,
                                                  float* __restrict__ Wall,
                                                  float* __restrict__ bWc,
                                                  int* __restrict__ cursor,
                                                  unsigned* __restrict__ srcW,
                                                  int n) {
    int t = threadIdx.x;
    if ((int)blockIdx.x >= 16) {
        int i = ((int)blockIdx.x - 16) * 256 + t;
        if (i < n) {
            cursor[i] = (i << CAPLOG) + 1;
            srcW[(size_t)i << CAPLOG] = (unsigned)i;
        }
        return;
    }
    __shared__ float w2f[128 * 8];
    int j = blockIdx.x;
    for (int i = t; i < 1024; i += 256) {
        int k = i >> 3, c = i & 7;
        float s = 0.f;
        for (int m = 0; m < 128; m++)
            s = fmaf(W2[k * 128 + m], Wfc[m * 8 + c], s);
        w2f[i] = s;
    }
    __syncthreads();
    if (t < 64) {
        int f = j * 8 + (t >> 3), c = t & 7;
        float s = 0.f;
        for (int k = 0; k < 128; k++)
            s = fmaf(W1[f * 128 + k], w2f[k * 8 + c], s);
        Wall[f * 8 + c] = s;
    }
    if (j == 0) {
        if (t >= 64 && t < 72) {           // bW[c] = sum_k b1[k] w2f[k][c]
            int c = t - 64;
            float s = 0.f;
            for (int k = 0; k < 128; k++) s = fmaf(b1[k], w2f[k * 8 + c], s);
            bWc[c] = s;
        } else if (t >= 72 && t < 80) {    // cvec[c] = sum_m b2[m] Wfc[m][c] + bfc[c]
            int c = t - 72;
            float s = bfc[c];
            for (int m = 0; m < 128; m++) s = fmaf(b2[m], Wfc[m * 8 + c], s);
            bWc[8 + c] = s;
        }
    }
}

// ---------- partitioned scatter (R17-proven pattern) ----------
// block b: partition p = b&7 (XCD-pure under round-robin dispatch), chunk
// ch = b>>3. Scans ECHUNK edges, keeps targets in [p*PART,(p+1)*PART),
// atomic-appends src id into the target's 64-slot bucket. cursor and srcW
// lines are node-contiguous -> single-partition -> L2-local atomics.
__global__ __launch_bounds__(256) void k_scatter(const int* __restrict__ ei,
                                                 int* __restrict__ cursor,
                                                 unsigned* __restrict__ srcW, int E,
                                                 int NCH, int PART) {
    int tid = threadIdx.x;
    int p = blockIdx.x & 7, ch = blockIdx.x >> 3;
    if (ch >= NCH) return;
    const int* cols = ei + E;
    int plo = p * PART;
    int ebase = ch * ECHUNK + tid * 8;
    int eend = ch * ECHUNK + ECHUNK; if (eend > E) eend = E;
#pragma unroll
    for (int gi = 0; gi < 2; gi++) {
        int e4 = ebase + gi * 4;
        if (e4 + 4 <= eend) {
            int4 cc = *(const int4*)(cols + e4);
            int cv[4] = {cc.x, cc.y, cc.z, cc.w};
#pragma unroll
            for (int u = 0; u < 4; u++) {
                if ((unsigned)(cv[u] - plo) < (unsigned)PART) {
                    int r = ei[e4 + u];
                    int pos = atomicAdd(&cursor[cv[u]], 1);
                    if (pos < ((cv[u] + 1) << CAPLOG)) srcW[pos] = (unsigned)r;
                }
            }
        } else {
            for (int e = e4; e < eend; e++) {
                int c = cols[e];
                if ((unsigned)(c - plo) < (unsigned)PART) {
                    int r = ei[e];
                    int pos = atomicAdd(&cursor[c], 1);
                    if (pos < ((c + 1) << CAPLOG)) srcW[pos] = (unsigned)r;
                }
            }
        }
    }
}

// ---------- Q projection: Qsc[i] = dinv[i] * (X[i]·Wall) ----------
// 32 nodes/block, 8 threads/node; X via nt-loads; wsh padded 16B/128 floats
// (bank-conflict-free). dinv inline from final cursor.
__global__ __launch_bounds__(256) void k_qproj(const int* __restrict__ cursor,
                                               const float* __restrict__ X,
                                               const float* __restrict__ Wall,
                                               float* __restrict__ Qsc,
                                               int nrows) {
    __shared__ float wsh[1024 + 32];
    int tid = threadIdx.x;
    {
        int i4 = tid * 4;
        float4 wv = ((const float4*)Wall)[tid];
        int o = i4 + ((i4 >> 7) << 2);
        wsh[o] = wv.x; wsh[o + 1] = wv.y; wsh[o + 2] = wv.z; wsh[o + 3] = wv.w;
    }
    __syncthreads();
    int sub = tid & 7;
    int node = blockIdx.x * 32 + (tid >> 3);
    if (node >= nrows) return;
    float acc[8];
#pragma unroll
    for (int c = 0; c < 8; c++) acc[c] = 0.f;
    const float* xr = X + (size_t)node * HDIM + sub * 16;
    const float* wbase = wsh + (sub * 16) * 8 + sub * 4;   // padded row base
#pragma unroll
    for (int j4 = 0; j4 < 4; j4++) {
        float4 xv = ntload4(xr + j4 * 4);
        const float* wr = wbase + j4 * 32;
#pragma unroll
        for (int c = 0; c < 8; c++) acc[c] = fmaf(xv.x, wr[c], acc[c]);
        wr += 8;
#pragma unroll
        for (int c = 0; c < 8; c++) acc[c] = fmaf(xv.y, wr[c], acc[c]);
        wr += 8;
#pragma unroll
        for (int c = 0; c < 8; c++) acc[c] = fmaf(xv.z, wr[c], acc[c]);
        wr += 8;
#pragma unroll
        for (int c = 0; c < 8; c++) acc[c] = fmaf(xv.w, wr[c], acc[c]);
    }
#pragma unroll
    for (int off = 1; off < 8; off <<= 1)
#pragma unroll
        for (int c = 0; c < 8; c++) acc[c] += __shfl_xor(acc[c], off, 64);
    if (sub < 2) {
        int s = node << CAPLOG;
        float di = rsqrtf((float)(cursor[node] - s));   // deg+1
        float4 o = make_float4(di * acc[sub * 4 + 0], di * acc[sub * 4 + 1],
                               di * acc[sub * 4 + 2], di * acc[sub * 4 + 3]);
        *(float4*)(Qsc + (size_t)node * 8 + sub * 4) = o;
    }
}

// ---------- 8-dim aggregation: 2 nodes per wave in PARALLEL (R20-proven) ----------
// lane: grp = lane>>5 selects node in pair; il = lane&31: sl = il>>1
// (16 slots/iter), half = il&1 (which float4 of the 32B row). j-loop is
// 2-ahead unrolled (j, j+16 issue together, second predicated). Reduce =
// exactly 4 shfl_xor rounds (2,4,8,16) over the slot bits; lanes il<2 store.
// MODE 0: Psc[i] = di*(di*sum + bW)   (pre-scaled for pass 2)
// MODE 1: out[i] = di*sum + cvec
template <int MODE>
__global__ __launch_bounds__(256) void k_agg8(const float* __restrict__ rows,
                                              const int* __restrict__ cursor,
                                              const unsigned* __restrict__ srcW,
                                              const float* __restrict__ bvec,
                                              float* __restrict__ outp,
                                              int n) {
    int tid = threadIdx.x, w = tid >> 6, lane = tid & 63;
    int grp = lane >> 5;
    int il = lane & 31, sl = il >> 1, half = il & 1;
    float4 bb = ((const float4*)bvec)[half];
    int node = blockIdx.x * 8 + w * 2 + grp;
    if (node >= n) return;
    int s = node << CAPLOG;
    int e = cursor[node];
    int ecap = s + (1 << CAPLOG);
    if (e > ecap) e = ecap;                    // paranoia clamp (never taken)
    float4 acc = make_float4(0.f, 0.f, 0.f, 0.f);
    for (int j = s + sl; j < e; j += 32) {
        unsigned id0 = srcW[j];
        int j2 = j + 16;
        unsigned id1 = (j2 < e) ? srcW[j2] : 0u;
        float4 v0 = *(const float4*)(rows + (size_t)id0 * 8 + half * 4);
        acc.x += v0.x; acc.y += v0.y; acc.z += v0.z; acc.w += v0.w;
        if (j2 < e) {
            float4 v1 = *(const float4*)(rows + (size_t)id1 * 8 + half * 4);
            acc.x += v1.x; acc.y += v1.y; acc.z += v1.z; acc.w += v1.w;
        }
    }
#pragma unroll
    for (int off = 2; off < 32; off <<= 1) {   // 2,4,8,16: complete reduce over sl
        acc.x += __shfl_xor(acc.x, off, 64);
        acc.y += __shfl_xor(acc.y, off, 64);
        acc.z += __shfl_xor(acc.z, off, 64);
        acc.w += __shfl_xor(acc.w, off, 64);
    }
    if (il < 2) {
        float di = rsqrtf((float)(e - s));     // deg+1
        float4 o;
        if (MODE == 0) {
            float a = di * di;
            o = make_float4(fmaf(a, acc.x, di * bb.x), fmaf(a, acc.y, di * bb.y),
                            fmaf(a, acc.z, di * bb.z), fmaf(a, acc.w, di * bb.w));
        } else {
            o = make_float4(fmaf(di, acc.x, bb.x), fmaf(di, acc.y, bb.y),
                            fmaf(di, acc.z, bb.z), fmaf(di, acc.w, bb.w));
        }
        *(float4*)(outp + (size_t)node * 8 + half * 4) = o;
    }
}

extern "C" void kernel_launch(void* const* d_in, const int* in_sizes, int n_in,
                              void* d_out, int out_size, void* d_ws, size_t ws_size,
                              hipStream_t stream) {
    const float* x   = (const float*)d_in[0];
    const int*   ei  = (const int*)d_in[1];
    const float* W1  = (const float*)d_in[2];
    const float* b1  = (const float*)d_in[3];
    const float* W2  = (const float*)d_in[4];
    const float* b2  = (const float*)d_in[5];
    const float* Wfc = (const float*)d_in[6];
    const float* bfc = (const float*)d_in[7];
    float* out = (float*)d_out;

    const int N = in_sizes[0] / HDIM;   // 50000
    const int E = in_sizes[1] / 2;      // 800000

    // workspace (~17 MB), no memsets needed
    float* Qsc    = (float*)d_ws;                        // N*8 f32
    float* Psc    = Qsc + (size_t)N * 8;                 // N*8 f32
    float* Wall   = Psc + (size_t)N * 8;                 // 1024
    float* bWc    = Wall + 1024;                         // 16 (bW | cvec)
    int*   cursor = (int*)(bWc + 16);                    // N
    unsigned* srcW = (unsigned*)(((uintptr_t)(cursor + N) + 255) & ~(uintptr_t)255);  // N*64

    const int NCH  = (E + ECHUNK - 1) / ECHUNK;  // 391 edge chunks
    const int PART = (N + 7) / 8;                // 6250 nodes per partition
    const int Gi   = 16 + (N + 255) / 256;       // 16 w2f + 196 init blocks
    const int Gq   = (N + 31) / 32;              // 1563
    const int Ga   = (N + 7) / 8;                // 6250: 4 waves x 2 nodes

    k_init_w2f<<<Gi, 256, 0, stream>>>(W1, b1, W2, b2, Wfc, bfc, Wall, bWc,
                                       cursor, srcW, N);
    k_scatter<<<8 * NCH, 256, 0, stream>>>(ei, cursor, srcW, E, NCH, PART);
    k_qproj<<<Gq, 256, 0, stream>>>(cursor, x, Wall, Qsc, N);
    k_agg8<0><<<Ga, 256, 0, stream>>>(Qsc, cursor, srcW, bWc, Psc, N);
    k_agg8<1><<<Ga, 256, 0, stream>>>(Psc, cursor, srcW, bWc + 8, out, N);
}